// Round 7
// baseline (8556.718 us; speedup 1.0000x reference)
//
#include <hip/hip_runtime.h>

// TrajectoryAttention on MI355X (gfx950), chunked pipeline, dtype-adaptive.
// R7: threefry idx0 switched to the MODERN JAX scheme (jax_threefry_partitionable=True,
//     default since jax 0.4.30): foldlike split (lane (0,i) per subkey) + partitionable
//     random_bits (lane (0,j), bits = o0 ^ o1). Selection stays f64. Smooth path bf16.

using u16 = unsigned short;
using u32 = unsigned int;

typedef short bf16x8 __attribute__((ext_vector_type(8)));
typedef float f32x4 __attribute__((ext_vector_type(4)));

#define N_ 3136
#define C_ 768
#define H_ 12
#define F_ 16
#define P_ 196
#define L_ 128
#define SC_ 0.35355339059327373f   // 64^-0.25 (f32, smooth path)
#define SC64_ 0.35355339059327376220 // 64^-0.25 (f64, selection path)
#define OUTPART_ ((size_t)2 * N_ * C_)

__device__ __forceinline__ float b2f(u16 u) {
  u32 x = ((u32)u) << 16; float f; __builtin_memcpy(&f, &x, 4); return f;
}
__device__ __forceinline__ float lo16f(u32 u) {
  u32 x = u << 16; float f; __builtin_memcpy(&f, &x, 4); return f;
}
__device__ __forceinline__ float hi16f(u32 u) {
  u32 x = u & 0xFFFF0000u; float f; __builtin_memcpy(&f, &x, 4); return f;
}
__device__ __forceinline__ u16 f2b(float f) {
  u32 u; __builtin_memcpy(&u, &f, 4);
  u32 r = (u + 0x7FFFu + ((u >> 16) & 1u)) >> 16;
  return (u16)r;
}

// load 16 contiguous logical elements as bf16 uint4 pair, from raw input of either dtype
__device__ __forceinline__ void ld16bf(const void* base, size_t elemOff, int isF32,
                                       uint4& o0, uint4& o1) {
  if (isF32) {
    const float4* p = (const float4*)((const float*)base + elemOff);
    float4 f0 = p[0], f1 = p[1], f2v = p[2], f3 = p[3];
    u16 tmp[16] = { f2b(f0.x), f2b(f0.y), f2b(f0.z), f2b(f0.w),
                    f2b(f1.x), f2b(f1.y), f2b(f1.z), f2b(f1.w),
                    f2b(f2v.x), f2b(f2v.y), f2b(f2v.z), f2b(f2v.w),
                    f2b(f3.x), f2b(f3.y), f2b(f3.z), f2b(f3.w) };
    __builtin_memcpy(&o0, tmp, 16);
    __builtin_memcpy(&o1, tmp + 8, 16);
  } else {
    const uint4* p = (const uint4*)((const u16*)base + elemOff);
    o0 = p[0]; o1 = p[1];
  }
}

// dtype sniffer (bf16 vs f32 inputs) — votes f32 on this dataset (proven R4)
__global__ void detect_k(const u32* __restrict__ w, int* __restrict__ flag) {
  const int t = threadIdx.x;  // 64
  int hits = 0;
  #pragma unroll
  for (int i = 0; i < 16; ++i) {
    u32 word = w[t * 16 + i];
    u32 e = (word >> 7) & 0xFFu;
    if (e >= 110u && e <= 126u) hits++;
  }
  #pragma unroll
  for (int off = 32; off > 0; off >>= 1) hits += __shfl_down(hits, off);
  if (t == 0) flag[0] = (hits >= 512) ? 0 : 1;  // 0=bf16, 1=f32
}

// ---- exact JAX threefry2x32-20 core ----
__device__ __forceinline__ void tf2(u32 k0, u32 k1v, u32 c0, u32 c1, u32& o0, u32& o1) {
  u32 ks[3] = {k0, k1v, k0 ^ k1v ^ 0x1BD11BDAu};
  u32 x0 = c0 + ks[0], x1 = c1 + ks[1];
  const u32 rA[4] = {13u, 15u, 26u, 6u}, rB[4] = {17u, 29u, 16u, 24u};
  #pragma unroll
  for (int r = 0; r < 5; ++r) {
    #pragma unroll
    for (int q = 0; q < 4; ++q) {
      u32 rot = (r & 1) ? rB[q] : rA[q];
      x0 += x1; x1 = (x1 << rot) | (x1 >> (32u - rot)); x1 ^= x0;
    }
    x0 += ks[(r + 1) % 3];
    x1 += ks[(r + 2) % 3] + (u32)(r + 1);
  }
  o0 = x0; o1 = x1;
}

// jax.random.randint(key(42), (24,), 0, 3136) under jax_threefry_partitionable=True
// (default since jax 0.4.30):
//   split foldlike: subkey i = threefry(key, hi=0, lo=i) -> (o0, o1)
//   random_bits partitionable (32-bit), elem j: threefry(subkey, hi=0, lo=j) -> o0 ^ o1
//   randint: ((hi % s) * (2^32 % s) + (lo % s)) % s ; 2^32 % 3136 = 2048
__device__ __forceinline__ int tf_idx0(int bh) {
  u32 a0, a1, b0, b1;
  tf2(0u, 42u, 0u, 0u, a0, a1);   // k1 = subkey 0
  tf2(0u, 42u, 0u, 1u, b0, b1);   // k2 = subkey 1
  u32 j = (u32)bh;
  u32 h0, h1, l0, l1;
  tf2(a0, a1, 0u, j, h0, h1);     // higher_bits[j]
  u32 hi = h0 ^ h1;
  tf2(b0, b1, 0u, j, l0, l1);     // lower_bits[j]
  u32 lo = l0 ^ l1;
  return (int)(((hi % 3136u) * 2048u + (lo % 3136u)) % 3136u);
}

// ---------------- selection-grade f64 GEMM: qd = (x @ W_qkv[:, :768]) * sc ----------------
__global__ __launch_bounds__(256) void qsel64_k(const void* __restrict__ xr, const void* __restrict__ wr,
                                                const int* __restrict__ flagp, double* __restrict__ qd)
{
  __shared__ double As[64 * 17];
  __shared__ double Bs[16 * 64];
  const int t = threadIdx.x;
  const int m0 = blockIdx.x * 64;
  const int n0 = blockIdx.y * 64;
  const int f32i = flagp[0];
  const int tx = t & 15, ty = t >> 4;
  double acc[4][4];
  #pragma unroll
  for (int i = 0; i < 4; ++i)
    #pragma unroll
    for (int j = 0; j < 4; ++j) acc[i][j] = 0.0;

  const int alr = t >> 2;               // A tile row (0..63)
  const int alk = (t & 3) * 4;          // A k offset
  const int bkr = t >> 4;               // B k row (0..15)
  const int bnc = (t & 15) * 4;         // B col offset

  for (int k0 = 0; k0 < 768; k0 += 16) {
    double av[4], bv[4];
    if (f32i) {
      const float* xa = (const float*)xr + (size_t)(m0 + alr) * 768 + k0 + alk;
      const float* wa = (const float*)wr + (size_t)(k0 + bkr) * 2304 + n0 + bnc;
      #pragma unroll
      for (int u = 0; u < 4; ++u) { av[u] = (double)xa[u]; bv[u] = (double)wa[u]; }
    } else {
      const u16* xa = (const u16*)xr + (size_t)(m0 + alr) * 768 + k0 + alk;
      const u16* wa = (const u16*)wr + (size_t)(k0 + bkr) * 2304 + n0 + bnc;
      #pragma unroll
      for (int u = 0; u < 4; ++u) { av[u] = (double)b2f(xa[u]); bv[u] = (double)b2f(wa[u]); }
    }
    #pragma unroll
    for (int u = 0; u < 4; ++u) As[alr * 17 + alk + u] = av[u];
    #pragma unroll
    for (int u = 0; u < 4; ++u) Bs[bkr * 64 + bnc + u] = bv[u];
    __syncthreads();
    #pragma unroll
    for (int kk = 0; kk < 16; ++kk) {
      double a[4], b[4];
      #pragma unroll
      for (int i = 0; i < 4; ++i) a[i] = As[(ty * 4 + i) * 17 + kk];
      #pragma unroll
      for (int j = 0; j < 4; ++j) b[j] = Bs[kk * 64 + tx * 4 + j];
      #pragma unroll
      for (int i = 0; i < 4; ++i)
        #pragma unroll
        for (int j = 0; j < 4; ++j) acc[i][j] += a[i] * b[j];
    }
    __syncthreads();
  }
  #pragma unroll
  for (int i = 0; i < 4; ++i) {
    const int m = m0 + ty * 4 + i;
    const int b = m / N_, n = m - b * N_;
    #pragma unroll
    for (int j = 0; j < 4; ++j) {
      const int col = n0 + tx * 4 + j;
      const int hh = col >> 6, dd = col & 63;
      qd[(((size_t)(b * H_ + hh)) * N_ + n) * 64 + dd] = acc[i][j] * SC64_;
    }
  }
}

// ---------------- greedy orthogonal landmarks: FULL f64, rows re-read from L2 each step ----------------
__global__ __launch_bounds__(512, 1) void landmarks64_k(const double* __restrict__ qd, float* __restrict__ lm)
{
  const int bh = blockIdx.x;
  const double* Q = qd + (size_t)bh * N_ * 64;
  float* LM = lm + (size_t)bh * L_ * 64;
  __shared__ double curD[64];
  __shared__ double redV[8];
  __shared__ int redI[8];
  __shared__ int sIdx;
  const int t = threadIdx.x;

  double inv[7], ms[7];
  #pragma unroll
  for (int i = 0; i < 7; ++i) {
    ms[i] = 0.0; inv[i] = 0.0;
    const int r = t + i * 512;
    if (r < N_) {
      const double2* rp = (const double2*)(Q + (size_t)r * 64);
      double s = 0.0;
      #pragma unroll
      for (int j = 0; j < 32; ++j) { double2 v = rp[j]; s += v.x * v.x + v.y * v.y; }
      inv[i] = 1.0 / fmax(sqrt(s), 1e-12);
    }
  }

  const int idx0 = tf_idx0(bh);
  #pragma unroll
  for (int i = 0; i < 7; ++i) if (t + i * 512 == idx0) ms[i] = 10.0;
  if (t < 64) {
    double v = Q[(size_t)idx0 * 64 + t];
    double s = v * v;
    #pragma unroll
    for (int off = 32; off; off >>= 1) s += __shfl_xor(s, off);
    curD[t] = v / fmax(sqrt(s), 1e-12);
    LM[t] = (float)v;
  }
  __syncthreads();

  for (int step = 1; step < 128; ++step) {
    double bV = 1e30; int bI = 0x7fffffff;
    #pragma unroll
    for (int i = 0; i < 7; ++i) {
      const int r = t + i * 512;
      if (r < N_) {
        const double2* rp = (const double2*)(Q + (size_t)r * 64);
        double d0 = 0.0, d1 = 0.0;
        #pragma unroll
        for (int j = 0; j < 32; ++j) {
          double2 v = rp[j];
          d0 += v.x * curD[2 * j];
          d1 += v.y * curD[2 * j + 1];
        }
        const double cosv = fabs((d0 + d1) * inv[i]);
        const double m = fmax(ms[i], cosv);
        ms[i] = m;
        if (m < bV || (m == bV && r < bI)) { bV = m; bI = r; }
      }
    }
    #pragma unroll
    for (int off = 32; off; off >>= 1) {
      const double ov = __shfl_xor(bV, off);
      const int oi = __shfl_xor(bI, off);
      if (ov < bV || (ov == bV && oi < bI)) { bV = ov; bI = oi; }
    }
    if ((t & 63) == 0) { redV[t >> 6] = bV; redI[t >> 6] = bI; }
    __syncthreads();
    if (t == 0) {
      double v = redV[0]; int ix = redI[0];
      #pragma unroll
      for (int w2 = 1; w2 < 8; ++w2)
        if (redV[w2] < v || (redV[w2] == v && redI[w2] < ix)) { v = redV[w2]; ix = redI[w2]; }
      sIdx = ix;
    }
    __syncthreads();
    const int mi = sIdx;
    #pragma unroll
    for (int i = 0; i < 7; ++i) if (t + i * 512 == mi) ms[i] = 10.0;
    if (t < 64) {
      double v = Q[(size_t)mi * 64 + t];
      double s = v * v;
      #pragma unroll
      for (int off = 32; off; off >>= 1) s += __shfl_xor(s, off);
      curD[t] = v / fmax(sqrt(s), 1e-12);
      LM[(size_t)step * 64 + t] = (float)v;
    }
    __syncthreads();
  }
}

// ---------------- generic 128x128 bf16 MFMA GEMM, per-mode epilogues ----------------
template <int MODE>
__global__ __launch_bounds__(256) void gemm_k(
    const void* __restrict__ Ap, const void* __restrict__ Bp,
    int M, int K, int lda, int ldb, int n0c, int cn, const int* __restrict__ flagp,
    float* __restrict__ of0, u16* __restrict__ ob0, u16* __restrict__ ob1, u16* __restrict__ ob2,
    const void* __restrict__ biasRaw, void* __restrict__ outRaw)
{
  constexpr bool A_RAW = (MODE == 0);
  constexpr bool B_RAW = (MODE == 0 || MODE >= 2);
  __shared__ u16 As[128 * 40];
  __shared__ u16 Bs[128 * 40];
  const int t = threadIdx.x;
  const int m0 = blockIdx.x * 128;
  const int n0 = blockIdx.y * 128;
  const int rf = (A_RAW || B_RAW) ? flagp[0] : 0;
  const int aF32 = A_RAW ? rf : 0;
  const int bF32 = B_RAW ? rf : 0;

  size_t aOff = 0, bOff = 0;
  if constexpr (MODE == 1) {
    const int bh = blockIdx.z;
    aOff = (size_t)bh * ((size_t)N_ * 128) + (size_t)n0c * 128;
    bOff = (size_t)bh * (128 * 1024);
  }
  const int lane = t & 63;
  const int w = t >> 6;
  const int mw = (w >> 1) * 64;
  const int nw = (w & 1) * 64;
  const int lr = lane & 15;
  const int lk = lane >> 4;

  f32x4 acc[4][4];
  #pragma unroll
  for (int i = 0; i < 4; ++i)
    #pragma unroll
    for (int j = 0; j < 4; ++j) acc[i][j] = (f32x4){0.f, 0.f, 0.f, 0.f};

  const int ar = t >> 1;
  const int ak = (t & 1) * 16;
  const int bk = t & 31;
  const int bn = (t >> 5) * 16;
  const int agrow = m0 + ar;
  const bool aValid = (agrow < M);

  for (int k0 = 0; k0 < K; k0 += 32) {
    uint4 a0, a1;
    if (aValid) {
      ld16bf(Ap, aOff + (size_t)agrow * lda + k0 + ak, aF32, a0, a1);
    } else {
      a0.x = a0.y = a0.z = a0.w = 0u; a1 = a0;
    }
    uint4 b0, b1;
    ld16bf(Bp, bOff + (size_t)(k0 + bk) * ldb + n0 + bn, bF32, b0, b1);

    *(uint4*)(&As[ar * 40 + ak]) = a0;
    *(uint4*)(&As[ar * 40 + ak + 8]) = a1;
    u16 tmp[16];
    *(uint4*)(tmp) = b0;
    *(uint4*)(tmp + 8) = b1;
    #pragma unroll
    for (int j = 0; j < 16; ++j) Bs[(bn + j) * 40 + bk] = tmp[j];  // Bs[n][k]
    __syncthreads();

    bf16x8 af[4], bfv[4];
    #pragma unroll
    for (int mt = 0; mt < 4; ++mt)
      af[mt] = *(const bf16x8*)(&As[(mw + mt * 16 + lr) * 40 + lk * 8]);
    #pragma unroll
    for (int nt = 0; nt < 4; ++nt)
      bfv[nt] = *(const bf16x8*)(&Bs[(nw + nt * 16 + lr) * 40 + lk * 8]);
    #pragma unroll
    for (int mt = 0; mt < 4; ++mt)
      #pragma unroll
      for (int nt = 0; nt < 4; ++nt)
        acc[mt][nt] = __builtin_amdgcn_mfma_f32_16x16x32_bf16(af[mt], bfv[nt], acc[mt][nt], 0, 0, 0);
    __syncthreads();
  }

  #pragma unroll
  for (int mt = 0; mt < 4; ++mt) {
    #pragma unroll
    for (int nt = 0; nt < 4; ++nt) {
      #pragma unroll
      for (int r = 0; r < 4; ++r) {
        const int grow = m0 + mw + mt * 16 + lk * 4 + r;
        const int gcol = n0 + nw + nt * 16 + lr;
        if (grow >= M) continue;
        float vv = acc[mt][nt][r];
        if constexpr (MODE == 0) {           // qkv -> qb,kb,vb bf16 (bh,N,64)
          int b = (grow >= N_) ? 1 : 0;
          int n = grow - b * N_;
          int t3 = gcol / C_, cc = gcol - t3 * C_;
          int hh = cc >> 6, dd = cc & 63;
          size_t dst = (((size_t)(b * H_ + hh)) * N_ + n) * 64 + dd;
          if (t3 == 0) ob0[dst] = f2b(vv * SC_);
          else if (t3 == 1) ob1[dst] = f2b(vv * SC_);
          else ob2[dst] = f2b(vv);
        } else if constexpr (MODE == 1) {    // xoc (B,cn,F,C) bf16 + xdiag side-write
          const int bh = blockIdx.z;
          int b = bh / H_, hh = bh - b * H_;
          int f = gcol >> 6, dd = gcol & 63;
          u16 wv = f2b(vv);
          ob0[(((size_t)(b * cn + grow)) * F_ + f) * C_ + hh * 64 + dd] = wv;
          int n = n0c + grow;
          if (f == n / P_) ob1[((size_t)(b * cn + grow)) * C_ + hh * 64 + dd] = wv;
        } else if constexpr (MODE == 2) {    // k2c,v2c (B,h,cn,F,d) bf16
          const int cn16 = cn * F_;
          int b = (grow >= cn16) ? 1 : 0;
          int r2 = grow - b * cn16;
          int ln = r2 >> 4, f = r2 & 15;
          int t2 = (gcol >= C_) ? 1 : 0, cc = gcol - t2 * C_;
          int hh = cc >> 6, dd = cc & 63;
          size_t dst = ((((size_t)(b * H_ + hh)) * cn + ln) * F_ + f) * 64 + dd;
          if (t2) ob1[dst] = f2b(vv); else ob0[dst] = f2b(vv);
        } else if constexpr (MODE == 3) {    // q2c (B,h,cn,d) f32, * 0.125
          int b = (grow >= cn) ? 1 : 0;
          int ln = grow - b * cn;
          int hh = gcol >> 6, dd = gcol & 63;
          of0[(((size_t)(b * H_ + hh)) * cn + ln) * 64 + dd] = vv * 0.125f;
        } else {                             // out = o@W_proj + b_proj, flag dtype
          float bvad = bF32 ? ((const float*)biasRaw)[gcol] : b2f(((const u16*)biasRaw)[gcol]);
          float ov = vv + bvad;
          if (bF32) ((float*)outRaw)[(size_t)grow * C_ + gcol] = ov;
          else      ((u16*)outRaw)[(size_t)grow * C_ + gcol] = f2b(ov);
        }
      }
    }
  }
}

// ---------------- kernel_1 = softmax_l(q . lm^T), bf16 out ----------------
__global__ __launch_bounds__(256) void k1_k(const u16* __restrict__ qb,
                                            const float* __restrict__ lm,
                                            u16* __restrict__ k1)
{
  const int bh = blockIdx.y;
  const int r0 = blockIdx.x * 64;
  __shared__ float qT[64][65];
  __shared__ float lmS[128 * 64];
  __shared__ float redA[4][64];
  __shared__ float redB[64];
  const int t = threadIdx.x;
  const u16* Q = qb + ((size_t)bh * N_ + r0) * 64;
  const float* Lm = lm + (size_t)bh * L_ * 64;
  for (int u = t; u < 2048; u += 256) ((float4*)lmS)[u] = ((const float4*)Lm)[u];
  for (int u = t; u < 512; u += 256) {
    int row = u >> 3, j0 = (u & 7) * 8;
    uint4 pk = *(const uint4*)(Q + (size_t)row * 64 + j0);
    const u16* pu = (const u16*)&pk;
    #pragma unroll
    for (int jj = 0; jj < 8; ++jj) qT[j0 + jj][row] = b2f(pu[jj]);
  }
  __syncthreads();
  const int row = t & 63, ch = t >> 6;
  float qr[64];
  #pragma unroll
  for (int j = 0; j < 64; ++j) qr[j] = qT[j][row];
  float s[32];
  for (int li = 0; li < 32; ++li) {
    const float* lp = lmS + (ch * 32 + li) * 64;
    float a = 0.f;
    #pragma unroll
    for (int j = 0; j < 64; ++j) a += lp[j] * qr[j];
    s[li] = a;
  }
  float mx = -1e30f;
  for (int li = 0; li < 32; ++li) mx = fmaxf(mx, s[li]);
  redA[ch][row] = mx;
  __syncthreads();
  if (t < 64) redB[t] = fmaxf(fmaxf(redA[0][t], redA[1][t]), fmaxf(redA[2][t], redA[3][t]));
  __syncthreads();
  mx = redB[row];
  float sum = 0.f;
  for (int li = 0; li < 32; ++li) { float e = __expf(s[li] - mx); s[li] = e; sum += e; }
  __syncthreads();
  redA[ch][row] = sum;
  __syncthreads();
  if (t < 64) redB[t] = 1.0f / (redA[0][t] + redA[1][t] + redA[2][t] + redA[3][t]);
  __syncthreads();
  const float inv = redB[row];
  u16* out = k1 + ((size_t)bh * N_ + r0 + row) * 128 + ch * 32;
  for (int li = 0; li < 32; ++li) out[li] = f2b(s[li] * inv);
}

// ---------------- kernel_2 per frame + x1 = kernel_2 @ v  (LDS-only, 3-pass) ----------------
__global__ __launch_bounds__(256) void k2x1_k(const float* __restrict__ lm,
                                              const u16* __restrict__ kb,
                                              const u16* __restrict__ vb,
                                              u16* __restrict__ x1)
{
  const int bh = blockIdx.x;
  const int f = blockIdx.y;
  __shared__ u16 kS[P_ * 64];
  __shared__ u16 vS[P_ * 64];
  __shared__ float redM[2][128];
  __shared__ float redS[2][128];
  const int t = threadIdx.x;
  const u16* Kf = kb + ((size_t)bh * N_ + f * P_) * 64;
  const u16* Vf = vb + ((size_t)bh * N_ + f * P_) * 64;
  for (int u = t; u < 1568; u += 256) {
    ((uint4*)kS)[u] = ((const uint4*)Kf)[u];
    ((uint4*)vS)[u] = ((const uint4*)Vf)[u];
  }
  __syncthreads();
  const int l = t & 127, half = t >> 7;
  const float* lp = lm + ((size_t)bh * L_ + l) * 64;
  float lr[64];
  #pragma unroll
  for (int j = 0; j < 64; ++j) lr[j] = lp[j];

  const int p0 = half * 98, p1 = p0 + 98;
  float mx = -1e30f;
  for (int p = p0; p < p1; ++p) {
    const uint4* kp = (const uint4*)(kS + p * 64);
    float s = 0.f;
    #pragma unroll
    for (int q4 = 0; q4 < 8; ++q4) {
      uint4 pk = kp[q4];
      const u32* pu = (const u32*)&pk;
      #pragma unroll
      for (int j2 = 0; j2 < 4; ++j2) {
        u32 u = pu[j2];
        s += lr[q4 * 8 + j2 * 2] * lo16f(u) + lr[q4 * 8 + j2 * 2 + 1] * hi16f(u);
      }
    }
    mx = fmaxf(mx, s);
  }
  redM[half][l] = mx;
  __syncthreads();
  mx = fmaxf(redM[0][l], redM[1][l]);

  float sm = 0.f;
  for (int p = p0; p < p1; ++p) {
    const uint4* kp = (const uint4*)(kS + p * 64);
    float s = 0.f;
    #pragma unroll
    for (int q4 = 0; q4 < 8; ++q4) {
      uint4 pk = kp[q4];
      const u32* pu = (const u32*)&pk;
      #pragma unroll
      for (int j2 = 0; j2 < 4; ++j2) {
        u32 u = pu[j2];
        s += lr[q4 * 8 + j2 * 2] * lo16f(u) + lr[q4 * 8 + j2 * 2 + 1] * hi16f(u);
      }
    }
    sm += __expf(s - mx);
  }
  redS[half][l] = sm;
  __syncthreads();
  const float inv = 1.0f / (redS[0][l] + redS[1][l]);

  const int dd0 = half * 32;
  float acc[32];
  #pragma unroll
  for (int u = 0; u < 32; ++u) acc[u] = 0.f;
  for (int p = 0; p < P_; ++p) {
    const uint4* kp = (const uint4*)(kS + p * 64);
    float s = 0.f;
    #pragma unroll
    for (int q4 = 0; q4 < 8; ++q4) {
      uint4 pk = kp[q4];
      const u32* pu = (const u32*)&pk;
      #pragma unroll
      for (int j2 = 0; j2 < 4; ++j2) {
        u32 u = pu[j2];
        s += lr[q4 * 8 + j2 * 2] * lo16f(u) + lr[q4 * 8 + j2 * 2 + 1] * hi16f(u);
      }
    }
    const float e = __expf(s - mx);
    const uint4* vp = (const uint4*)(vS + p * 64 + dd0);
    #pragma unroll
    for (int q4 = 0; q4 < 4; ++q4) {
      uint4 pv = vp[q4];
      const u32* pu = (const u32*)&pv;
      #pragma unroll
      for (int j2 = 0; j2 < 4; ++j2) {
        u32 u = pu[j2];
        acc[q4 * 8 + j2 * 2]     += e * lo16f(u);
        acc[q4 * 8 + j2 * 2 + 1] += e * hi16f(u);
      }
    }
  }
  u16* out = x1 + (((size_t)bh * L_ + l) * F_ + f) * 64 + dd0;
  for (int u = 0; u < 32; ++u) out[u] = f2b(acc[u] * inv);
}

// ---------------- final 16-way frame attention + o = attn @ v2 (chunked) ----------------
__global__ __launch_bounds__(256) void attn_k(const float* __restrict__ q2c,
                                              const u16* __restrict__ k2c,
                                              const u16* __restrict__ v2c,
                                              int n0c, int cn, const int* __restrict__ flagp,
                                              void* __restrict__ outRaw,
                                              u16* __restrict__ o)
{
  const int bh = blockIdx.y;
  const int b = bh / H_, hh = bh - b * H_;
  const int t = threadIdx.x;
  const int f32o = flagp[0];
  __shared__ float aS[64][17];
  const int nl = t >> 2, qi = t & 3;
  const int ln = blockIdx.x * 64 + nl;
  const bool act = ln < cn;
  const int n = n0c + ln;
  float q[64];
  if (act) {
    const float* qr = q2c + ((size_t)bh * cn + ln) * 64;
    #pragma unroll
    for (int j = 0; j < 64; ++j) q[j] = qr[j];
    float lg[4];
    #pragma unroll
    for (int ff = 0; ff < 4; ++ff) {
      const int f = qi * 4 + ff;
      const u16* kp = k2c + (((size_t)bh * cn + ln) * F_ + f) * 64;
      float s = 0.f;
      #pragma unroll
      for (int j8 = 0; j8 < 8; ++j8) {
        uint4 pk = ((const uint4*)kp)[j8];
        const u16* pu = (const u16*)&pk;
        #pragma unroll
        for (int u = 0; u < 8; ++u) s += q[j8 * 8 + u] * b2f(pu[u]);
      }
      lg[ff] = s;
    }
    float mx = fmaxf(fmaxf(lg[0], lg[1]), fmaxf(lg[2], lg[3]));
    mx = fmaxf(mx, __shfl_xor(mx, 1));
    mx = fmaxf(mx, __shfl_xor(mx, 2));
    float e[4], sm = 0.f;
    #pragma unroll
    for (int ff = 0; ff < 4; ++ff) { e[ff] = __expf(lg[ff] - mx); sm += e[ff]; }
    sm += __shfl_xor(sm, 1);
    sm += __shfl_xor(sm, 2);
    const float iv = 1.0f / sm;
    const size_t abase = ((size_t)bh * N_ + n) * F_ + qi * 4;
    #pragma unroll
    for (int ff = 0; ff < 4; ++ff) {
      const float a = e[ff] * iv;
      if (f32o) ((float*)outRaw)[OUTPART_ + abase + ff] = a;
      else      ((u16*)outRaw)[OUTPART_ + abase + ff] = f2b(a);
      aS[nl][qi * 4 + ff] = a;
    }
  }
  __syncthreads();
  if (act) {
    const int dd0 = qi * 16;
    float acc[16];
    #pragma unroll
    for (int u = 0; u < 16; ++u) acc[u] = 0.f;
    for (int f = 0; f < F_; ++f) {
      const float w2 = aS[nl][f];
      const u16* vp = v2c + (((size_t)bh * cn + ln) * F_ + f) * 64 + dd0;
      uint4 pv0 = ((const uint4*)vp)[0], pv1 = ((const uint4*)vp)[1];
      const u16* pu0 = (const u16*)&pv0;
      const u16* pu1 = (const u16*)&pv1;
      #pragma unroll
      for (int u = 0; u < 8; ++u) acc[u] += w2 * b2f(pu0[u]);
      #pragma unroll
      for (int u = 0; u < 8; ++u) acc[8 + u] += w2 * b2f(pu1[u]);
    }
    u16* op = o + ((size_t)(b * N_ + n)) * C_ + hh * 64 + dd0;
    for (int u = 0; u < 16; ++u) op[u] = f2b(acc[u]);
  }
}

extern "C" void kernel_launch(void* const* d_in, const int* in_sizes, int n_in,
                              void* d_out, int out_size, void* d_ws, size_t ws_size,
                              hipStream_t stream)
{
  (void)in_sizes; (void)n_in; (void)out_size;
  const void* x     = d_in[0];
  const void* Wqkv  = d_in[1];
  const void* Wpq   = d_in[2];
  const void* Wpkv  = d_in[3];
  const void* Wproj = d_in[4];
  const void* bproj = d_in[5];

  char* ws = (char*)d_ws;
  size_t off = 0;
  auto alloc = [&](size_t bytes) { void* p = ws + off; off += (bytes + 255) & ~(size_t)255; return p; };
  int*  flagp = (int*)alloc(256);
  u16*  qb  = (u16*)alloc(9633792);     // (bh,N,64) bf16, scaled
  u16*  kb  = (u16*)alloc(9633792);     // scaled
  u16*  vb  = (u16*)alloc(9633792);
  float* lm = (float*)alloc(786432);    // (bh,128,64) f32
  u16*  x1b = (u16*)alloc(6291456);     // (bh,128,16,64) bf16
  u16*  ob  = (u16*)alloc(9633792);     // (B,N,C) bf16
  const size_t k1off = off;             // qd f64 starts here (aliases k1b + chunk region)
  u16*  k1b = (u16*)alloc(19267584);    // (bh,N,128) bf16
  const size_t chunk0 = off;

  // qd (selection f64) needs 38,535,168 B at k1off; dead before k1b & chunk region live
  const size_t qdNeed = k1off + 38535168 + 256;

  int Nc = 0;
  {
    const int cands[5] = {3136, 1568, 784, 392, 196};
    for (int i = 0; i < 5; ++i) {
      size_t need = chunk0 + (size_t)156672 * cands[i] + 1024;
      if (need <= ws_size && qdNeed <= ws_size) { Nc = cands[i]; break; }
    }
  }
  if (Nc == 0) return;  // ws floor ~95.7 MB
  const int nchunks = N_ / Nc;
  u16*  xoc = (u16*)(ws + chunk0);                // (B,Nc,F,C) bf16
  u16*  k2c = xoc + (size_t)24576 * Nc;           // (B,h,Nc,F,d) bf16
  u16*  v2c = k2c + (size_t)24576 * Nc;
  u16*  xdc = v2c + (size_t)24576 * Nc;           // (B,Nc,C) bf16
  float* q2c = (float*)(xdc + (size_t)1536 * Nc); // (B,h,Nc,d) f32
  double* qd = (double*)(ws + k1off);             // selection-grade f64 q (dead before k1_k)

  // dtype sniff on W_qkv
  detect_k<<<1, 64, 0, stream>>>((const u32*)Wqkv, flagp);

  // selection-grade f64 q, then greedy landmarks (f64, partitionable-threefry idx0)
  qsel64_k<<<dim3(98, 12), 256, 0, stream>>>(x, Wqkv, flagp, qd);
  landmarks64_k<<<24, 512, 0, stream>>>(qd, lm);

  // qkv projection -> qb,kb,vb (bf16 smooth path)
  gemm_k<0><<<dim3(49, 18, 1), 256, 0, stream>>>(x, Wqkv, 6272, 768, 768, 2304, 0, 0, flagp,
                                                 nullptr, qb, kb, vb, nullptr, nullptr);
  // kernel_2 + x1 (LDS-only)
  k2x1_k<<<dim3(24, 16), 256, 0, stream>>>(lm, kb, vb, x1b);
  // kernel_1 (overwrites qd region — qd dead)
  k1_k<<<dim3(49, 24), 256, 0, stream>>>(qb, lm, k1b);

  for (int c = 0; c < nchunks; ++c) {
    const int n0c = c * Nc;
    gemm_k<1><<<dim3((Nc + 127) / 128, 8, 24), 256, 0, stream>>>(
        k1b, x1b, Nc, 128, 128, 1024, n0c, Nc, flagp, nullptr, xoc, xdc, nullptr, nullptr, nullptr);
    gemm_k<2><<<dim3((2 * Nc * 16) / 128, 12, 1), 256, 0, stream>>>(
        xoc, Wpkv, 2 * Nc * 16, 768, 768, 1536, n0c, Nc, flagp, nullptr, k2c, v2c, nullptr, nullptr, nullptr);
    gemm_k<3><<<dim3((2 * Nc + 127) / 128, 6, 1), 256, 0, stream>>>(
        xdc, Wpq, 2 * Nc, 768, 768, 768, n0c, Nc, flagp, q2c, nullptr, nullptr, nullptr, nullptr, nullptr);
    attn_k<<<dim3((Nc + 63) / 64, 24), 256, 0, stream>>>(
        q2c, k2c, v2c, n0c, Nc, flagp, d_out, ob);
  }
  // out = o @ W_proj + b_proj
  gemm_k<4><<<dim3(49, 6, 1), 256, 0, stream>>>(ob, Wproj, 6272, 768, 768, 768, 0, 0, flagp,
                                                nullptr, nullptr, nullptr, nullptr, bproj, d_out);
}

// Round 8
// 2819.928 us; speedup vs baseline: 3.0344x; 3.0344x over previous
//
#include <hip/hip_runtime.h>

// TrajectoryAttention on MI355X (gfx950), chunked pipeline, dtype-adaptive.
// R8: landmarks path restructured for memory coalescing:
//   qselT_k: f32 VALU GEMM -> qT[bh][d][n] TRANSPOSED layout (f32, 19.3 MB)
//   landmarksT_k: per-step dots read qT coalesced (64 lanes x float4 = 1KB/wave-load),
//     f32 data + f64 accumulation (R5<->R6 bit-identity proved f32-safe), L2-resident.
// R7 (kept): partitionable threefry idx0; bf16 MFMA smooth path; chunked k2/v2.

using u16 = unsigned short;
using u32 = unsigned int;

typedef short bf16x8 __attribute__((ext_vector_type(8)));
typedef float f32x4 __attribute__((ext_vector_type(4)));

#define N_ 3136
#define C_ 768
#define H_ 12
#define F_ 16
#define P_ 196
#define L_ 128
#define SC_ 0.35355339059327373f   // 64^-0.25
#define OUTPART_ ((size_t)2 * N_ * C_)

__device__ __forceinline__ float b2f(u16 u) {
  u32 x = ((u32)u) << 16; float f; __builtin_memcpy(&f, &x, 4); return f;
}
__device__ __forceinline__ float lo16f(u32 u) {
  u32 x = u << 16; float f; __builtin_memcpy(&f, &x, 4); return f;
}
__device__ __forceinline__ float hi16f(u32 u) {
  u32 x = u & 0xFFFF0000u; float f; __builtin_memcpy(&f, &x, 4); return f;
}
__device__ __forceinline__ u16 f2b(float f) {
  u32 u; __builtin_memcpy(&u, &f, 4);
  u32 r = (u + 0x7FFFu + ((u >> 16) & 1u)) >> 16;
  return (u16)r;
}

// load 16 contiguous logical elements as bf16 uint4 pair, from raw input of either dtype
__device__ __forceinline__ void ld16bf(const void* base, size_t elemOff, int isF32,
                                       uint4& o0, uint4& o1) {
  if (isF32) {
    const float4* p = (const float4*)((const float*)base + elemOff);
    float4 f0 = p[0], f1 = p[1], f2v = p[2], f3 = p[3];
    u16 tmp[16] = { f2b(f0.x), f2b(f0.y), f2b(f0.z), f2b(f0.w),
                    f2b(f1.x), f2b(f1.y), f2b(f1.z), f2b(f1.w),
                    f2b(f2v.x), f2b(f2v.y), f2b(f2v.z), f2b(f2v.w),
                    f2b(f3.x), f2b(f3.y), f2b(f3.z), f2b(f3.w) };
    __builtin_memcpy(&o0, tmp, 16);
    __builtin_memcpy(&o1, tmp + 8, 16);
  } else {
    const uint4* p = (const uint4*)((const u16*)base + elemOff);
    o0 = p[0]; o1 = p[1];
  }
}

// dtype sniffer (bf16 vs f32 inputs) — votes f32 on this dataset (proven R4)
__global__ void detect_k(const u32* __restrict__ w, int* __restrict__ flag) {
  const int t = threadIdx.x;  // 64
  int hits = 0;
  #pragma unroll
  for (int i = 0; i < 16; ++i) {
    u32 word = w[t * 16 + i];
    u32 e = (word >> 7) & 0xFFu;
    if (e >= 110u && e <= 126u) hits++;
  }
  #pragma unroll
  for (int off = 32; off > 0; off >>= 1) hits += __shfl_down(hits, off);
  if (t == 0) flag[0] = (hits >= 512) ? 0 : 1;  // 0=bf16, 1=f32
}

// ---- exact JAX threefry2x32-20 core ----
__device__ __forceinline__ void tf2(u32 k0, u32 k1v, u32 c0, u32 c1, u32& o0, u32& o1) {
  u32 ks[3] = {k0, k1v, k0 ^ k1v ^ 0x1BD11BDAu};
  u32 x0 = c0 + ks[0], x1 = c1 + ks[1];
  const u32 rA[4] = {13u, 15u, 26u, 6u}, rB[4] = {17u, 29u, 16u, 24u};
  #pragma unroll
  for (int r = 0; r < 5; ++r) {
    #pragma unroll
    for (int q = 0; q < 4; ++q) {
      u32 rot = (r & 1) ? rB[q] : rA[q];
      x0 += x1; x1 = (x1 << rot) | (x1 >> (32u - rot)); x1 ^= x0;
    }
    x0 += ks[(r + 1) % 3];
    x1 += ks[(r + 2) % 3] + (u32)(r + 1);
  }
  o0 = x0; o1 = x1;
}

// jax.random.randint(key(42), (24,), 0, 3136) under jax_threefry_partitionable=True
// — PROVEN correct on this dataset (R7 passed at smooth-path floor).
__device__ __forceinline__ int tf_idx0(int bh) {
  u32 a0, a1, b0, b1;
  tf2(0u, 42u, 0u, 0u, a0, a1);   // k1 = subkey 0
  tf2(0u, 42u, 0u, 1u, b0, b1);   // k2 = subkey 1
  u32 j = (u32)bh;
  u32 h0, h1, l0, l1;
  tf2(a0, a1, 0u, j, h0, h1);     // higher_bits[j]
  u32 hi = h0 ^ h1;
  tf2(b0, b1, 0u, j, l0, l1);     // lower_bits[j]
  u32 lo = l0 ^ l1;
  return (int)(((hi % 3136u) * 2048u + (lo % 3136u)) % 3136u);
}

// ---------------- selection-grade f32 GEMM -> TRANSPOSED qT[bh][d][n] ----------------
__global__ __launch_bounds__(256) void qselT_k(const void* __restrict__ xr, const void* __restrict__ wr,
                                               const int* __restrict__ flagp, float* __restrict__ qt)
{
  __shared__ float As[64 * 20];
  __shared__ float Bs[16 * 64];
  const int t = threadIdx.x;
  const int m0 = blockIdx.x * 64;
  const int n0 = blockIdx.y * 64;
  const int f32i = flagp[0];
  const int tx = t & 15, ty = t >> 4;
  float acc[4][4];
  #pragma unroll
  for (int i = 0; i < 4; ++i)
    #pragma unroll
    for (int j = 0; j < 4; ++j) acc[i][j] = 0.f;

  const int alr = t >> 2;               // A tile row (0..63)
  const int alk = (t & 3) * 4;          // A k offset
  const int bkr = t >> 4;               // B k row (0..15)
  const int bnc = (t & 15) * 4;         // B col offset

  for (int k0 = 0; k0 < 768; k0 += 16) {
    float4 av, bv;
    if (f32i) {
      av = *(const float4*)((const float*)xr + (size_t)(m0 + alr) * 768 + k0 + alk);
      bv = *(const float4*)((const float*)wr + (size_t)(k0 + bkr) * 2304 + n0 + bnc);
    } else {
      const u16* xa = (const u16*)xr + (size_t)(m0 + alr) * 768 + k0 + alk;
      const u16* wa = (const u16*)wr + (size_t)(k0 + bkr) * 2304 + n0 + bnc;
      av.x = b2f(xa[0]); av.y = b2f(xa[1]); av.z = b2f(xa[2]); av.w = b2f(xa[3]);
      bv.x = b2f(wa[0]); bv.y = b2f(wa[1]); bv.z = b2f(wa[2]); bv.w = b2f(wa[3]);
    }
    As[alr * 20 + alk + 0] = av.x; As[alr * 20 + alk + 1] = av.y;
    As[alr * 20 + alk + 2] = av.z; As[alr * 20 + alk + 3] = av.w;
    *(float4*)(&Bs[bkr * 64 + bnc]) = bv;
    __syncthreads();
    #pragma unroll
    for (int kk = 0; kk < 16; ++kk) {
      float a[4], b[4];
      #pragma unroll
      for (int i = 0; i < 4; ++i) a[i] = As[(ty * 4 + i) * 20 + kk];
      #pragma unroll
      for (int j = 0; j < 4; ++j) b[j] = Bs[kk * 64 + tx * 4 + j];
      #pragma unroll
      for (int i = 0; i < 4; ++i)
        #pragma unroll
        for (int j = 0; j < 4; ++j) acc[i][j] += a[i] * b[j];
    }
    __syncthreads();
  }
  #pragma unroll
  for (int i = 0; i < 4; ++i) {
    const int m = m0 + ty * 4 + i;
    const int b = m / N_, n = m - b * N_;
    #pragma unroll
    for (int j = 0; j < 4; ++j) {
      const int col = n0 + tx * 4 + j;
      const int hh = col >> 6, dd = col & 63;
      qt[((size_t)(b * H_ + hh) * 64 + dd) * N_ + n] = acc[i][j] * SC_;
    }
  }
}

// ---------------- greedy landmarks: coalesced transposed reads, f64 accumulation ----------------
// 512 threads/block, 1 block/head. Rows: pass0 = 4t..4t+3 (rows 0..2047);
// pass1 = 2048+4t..2048+4t+3 (t<272). Per-d wave-load = 64 lanes x float4 contiguous.
__global__ __launch_bounds__(512, 1) void landmarksT_k(const float* __restrict__ qt, float* __restrict__ lm)
{
  const int bh = blockIdx.x;
  const float* QT = qt + (size_t)bh * 64 * N_;   // [d][n]
  float* LM = lm + (size_t)bh * L_ * 64;
  __shared__ double curD[64];
  __shared__ double redV[8];
  __shared__ int redI[8];
  __shared__ int sIdx;
  const int t = threadIdx.x;
  const int r0a = 4 * t;
  const int r0b = 2048 + 4 * t;
  const bool act1 = (t < 272);

  // norms (f64 from f32 data), coalesced
  double inv0[4], inv1[4], ms0[4], ms1[4];
  {
    double s[4] = {0.0, 0.0, 0.0, 0.0};
    const float* base = QT + r0a;
    #pragma unroll 8
    for (int d = 0; d < 64; ++d) {
      float4 v = *(const float4*)(base + (size_t)d * N_);
      s[0] += (double)v.x * (double)v.x; s[1] += (double)v.y * (double)v.y;
      s[2] += (double)v.z * (double)v.z; s[3] += (double)v.w * (double)v.w;
    }
    #pragma unroll
    for (int j = 0; j < 4; ++j) { inv0[j] = 1.0 / fmax(sqrt(s[j]), 1e-12); ms0[j] = 0.0; }
  }
  if (act1) {
    double s[4] = {0.0, 0.0, 0.0, 0.0};
    const float* base = QT + r0b;
    #pragma unroll 8
    for (int d = 0; d < 64; ++d) {
      float4 v = *(const float4*)(base + (size_t)d * N_);
      s[0] += (double)v.x * (double)v.x; s[1] += (double)v.y * (double)v.y;
      s[2] += (double)v.z * (double)v.z; s[3] += (double)v.w * (double)v.w;
    }
    #pragma unroll
    for (int j = 0; j < 4; ++j) { inv1[j] = 1.0 / fmax(sqrt(s[j]), 1e-12); ms1[j] = 0.0; }
  } else {
    #pragma unroll
    for (int j = 0; j < 4; ++j) { inv1[j] = 0.0; ms1[j] = 0.0; }
  }

  const int idx0 = tf_idx0(bh);
  #pragma unroll
  for (int j = 0; j < 4; ++j) {
    if (r0a + j == idx0) ms0[j] = 10.0;
    if (act1 && r0b + j == idx0) ms1[j] = 10.0;
  }
  if (t < 64) {
    float vf = QT[(size_t)t * N_ + idx0];
    double v = (double)vf;
    double s = v * v;
    #pragma unroll
    for (int off = 32; off; off >>= 1) s += __shfl_xor(s, off);
    curD[t] = v / fmax(sqrt(s), 1e-12);
    LM[t] = vf;
  }
  __syncthreads();

  for (int step = 1; step < 128; ++step) {
    double bV = 1e30; int bI = 0x7fffffff;
    {
      const float* base = QT + r0a;
      double a0 = 0.0, a1 = 0.0, a2 = 0.0, a3 = 0.0;
      #pragma unroll 8
      for (int d = 0; d < 64; ++d) {
        const double c = curD[d];
        float4 v = *(const float4*)(base + (size_t)d * N_);
        a0 += (double)v.x * c; a1 += (double)v.y * c;
        a2 += (double)v.z * c; a3 += (double)v.w * c;
      }
      double cs[4] = {fabs(a0 * inv0[0]), fabs(a1 * inv0[1]), fabs(a2 * inv0[2]), fabs(a3 * inv0[3])};
      #pragma unroll
      for (int j = 0; j < 4; ++j) {
        double m = fmax(ms0[j], cs[j]); ms0[j] = m;
        const int r = r0a + j;
        if (m < bV || (m == bV && r < bI)) { bV = m; bI = r; }
      }
    }
    if (act1) {
      const float* base = QT + r0b;
      double a0 = 0.0, a1 = 0.0, a2 = 0.0, a3 = 0.0;
      #pragma unroll 8
      for (int d = 0; d < 64; ++d) {
        const double c = curD[d];
        float4 v = *(const float4*)(base + (size_t)d * N_);
        a0 += (double)v.x * c; a1 += (double)v.y * c;
        a2 += (double)v.z * c; a3 += (double)v.w * c;
      }
      double cs[4] = {fabs(a0 * inv1[0]), fabs(a1 * inv1[1]), fabs(a2 * inv1[2]), fabs(a3 * inv1[3])};
      #pragma unroll
      for (int j = 0; j < 4; ++j) {
        double m = fmax(ms1[j], cs[j]); ms1[j] = m;
        const int r = r0b + j;
        if (m < bV || (m == bV && r < bI)) { bV = m; bI = r; }
      }
    }
    #pragma unroll
    for (int off = 32; off; off >>= 1) {
      const double ov = __shfl_xor(bV, off);
      const int oi = __shfl_xor(bI, off);
      if (ov < bV || (ov == bV && oi < bI)) { bV = ov; bI = oi; }
    }
    if ((t & 63) == 0) { redV[t >> 6] = bV; redI[t >> 6] = bI; }
    __syncthreads();
    if (t == 0) {
      double v = redV[0]; int ix = redI[0];
      #pragma unroll
      for (int w2 = 1; w2 < 8; ++w2)
        if (redV[w2] < v || (redV[w2] == v && redI[w2] < ix)) { v = redV[w2]; ix = redI[w2]; }
      sIdx = ix;
    }
    __syncthreads();
    const int mi = sIdx;
    #pragma unroll
    for (int j = 0; j < 4; ++j) {
      if (r0a + j == mi) ms0[j] = 10.0;
      if (act1 && r0b + j == mi) ms1[j] = 10.0;
    }
    if (t < 64) {
      float vf = QT[(size_t)t * N_ + mi];
      double v = (double)vf;
      double s = v * v;
      #pragma unroll
      for (int off = 32; off; off >>= 1) s += __shfl_xor(s, off);
      curD[t] = v / fmax(sqrt(s), 1e-12);
      LM[(size_t)step * 64 + t] = vf;
    }
    __syncthreads();
  }
}

// ---------------- generic 128x128 bf16 MFMA GEMM, per-mode epilogues ----------------
template <int MODE>
__global__ __launch_bounds__(256) void gemm_k(
    const void* __restrict__ Ap, const void* __restrict__ Bp,
    int M, int K, int lda, int ldb, int n0c, int cn, const int* __restrict__ flagp,
    float* __restrict__ of0, u16* __restrict__ ob0, u16* __restrict__ ob1, u16* __restrict__ ob2,
    const void* __restrict__ biasRaw, void* __restrict__ outRaw)
{
  constexpr bool A_RAW = (MODE == 0);
  constexpr bool B_RAW = (MODE == 0 || MODE >= 2);
  __shared__ u16 As[128 * 40];
  __shared__ u16 Bs[128 * 40];
  const int t = threadIdx.x;
  const int m0 = blockIdx.x * 128;
  const int n0 = blockIdx.y * 128;
  const int rf = (A_RAW || B_RAW) ? flagp[0] : 0;
  const int aF32 = A_RAW ? rf : 0;
  const int bF32 = B_RAW ? rf : 0;

  size_t aOff = 0, bOff = 0;
  if constexpr (MODE == 1) {
    const int bh = blockIdx.z;
    aOff = (size_t)bh * ((size_t)N_ * 128) + (size_t)n0c * 128;
    bOff = (size_t)bh * (128 * 1024);
  }
  const int lane = t & 63;
  const int w = t >> 6;
  const int mw = (w >> 1) * 64;
  const int nw = (w & 1) * 64;
  const int lr = lane & 15;
  const int lk = lane >> 4;

  f32x4 acc[4][4];
  #pragma unroll
  for (int i = 0; i < 4; ++i)
    #pragma unroll
    for (int j = 0; j < 4; ++j) acc[i][j] = (f32x4){0.f, 0.f, 0.f, 0.f};

  const int ar = t >> 1;
  const int ak = (t & 1) * 16;
  const int bk = t & 31;
  const int bn = (t >> 5) * 16;
  const int agrow = m0 + ar;
  const bool aValid = (agrow < M);

  for (int k0 = 0; k0 < K; k0 += 32) {
    uint4 a0, a1;
    if (aValid) {
      ld16bf(Ap, aOff + (size_t)agrow * lda + k0 + ak, aF32, a0, a1);
    } else {
      a0.x = a0.y = a0.z = a0.w = 0u; a1 = a0;
    }
    uint4 b0, b1;
    ld16bf(Bp, bOff + (size_t)(k0 + bk) * ldb + n0 + bn, bF32, b0, b1);

    *(uint4*)(&As[ar * 40 + ak]) = a0;
    *(uint4*)(&As[ar * 40 + ak + 8]) = a1;
    u16 tmp[16];
    *(uint4*)(tmp) = b0;
    *(uint4*)(tmp + 8) = b1;
    #pragma unroll
    for (int j = 0; j < 16; ++j) Bs[(bn + j) * 40 + bk] = tmp[j];  // Bs[n][k]
    __syncthreads();

    bf16x8 af[4], bfv[4];
    #pragma unroll
    for (int mt = 0; mt < 4; ++mt)
      af[mt] = *(const bf16x8*)(&As[(mw + mt * 16 + lr) * 40 + lk * 8]);
    #pragma unroll
    for (int nt = 0; nt < 4; ++nt)
      bfv[nt] = *(const bf16x8*)(&Bs[(nw + nt * 16 + lr) * 40 + lk * 8]);
    #pragma unroll
    for (int mt = 0; mt < 4; ++mt)
      #pragma unroll
      for (int nt = 0; nt < 4; ++nt)
        acc[mt][nt] = __builtin_amdgcn_mfma_f32_16x16x32_bf16(af[mt], bfv[nt], acc[mt][nt], 0, 0, 0);
    __syncthreads();
  }

  #pragma unroll
  for (int mt = 0; mt < 4; ++mt) {
    #pragma unroll
    for (int nt = 0; nt < 4; ++nt) {
      #pragma unroll
      for (int r = 0; r < 4; ++r) {
        const int grow = m0 + mw + mt * 16 + lk * 4 + r;
        const int gcol = n0 + nw + nt * 16 + lr;
        if (grow >= M) continue;
        float vv = acc[mt][nt][r];
        if constexpr (MODE == 0) {           // qkv -> qb,kb,vb bf16 (bh,N,64)
          int b = (grow >= N_) ? 1 : 0;
          int n = grow - b * N_;
          int t3 = gcol / C_, cc = gcol - t3 * C_;
          int hh = cc >> 6, dd = cc & 63;
          size_t dst = (((size_t)(b * H_ + hh)) * N_ + n) * 64 + dd;
          if (t3 == 0) ob0[dst] = f2b(vv * SC_);
          else if (t3 == 1) ob1[dst] = f2b(vv * SC_);
          else ob2[dst] = f2b(vv);
        } else if constexpr (MODE == 1) {    // xoc (B,cn,F,C) bf16 + xdiag side-write
          const int bh = blockIdx.z;
          int b = bh / H_, hh = bh - b * H_;
          int f = gcol >> 6, dd = gcol & 63;
          u16 wv = f2b(vv);
          ob0[(((size_t)(b * cn + grow)) * F_ + f) * C_ + hh * 64 + dd] = wv;
          int n = n0c + grow;
          if (f == n / P_) ob1[((size_t)(b * cn + grow)) * C_ + hh * 64 + dd] = wv;
        } else if constexpr (MODE == 2) {    // k2c,v2c (B,h,cn,F,d) bf16
          const int cn16 = cn * F_;
          int b = (grow >= cn16) ? 1 : 0;
          int r2 = grow - b * cn16;
          int ln = r2 >> 4, f = r2 & 15;
          int t2 = (gcol >= C_) ? 1 : 0, cc = gcol - t2 * C_;
          int hh = cc >> 6, dd = cc & 63;
          size_t dst = ((((size_t)(b * H_ + hh)) * cn + ln) * F_ + f) * 64 + dd;
          if (t2) ob1[dst] = f2b(vv); else ob0[dst] = f2b(vv);
        } else if constexpr (MODE == 3) {    // q2c (B,h,cn,d) f32, * 0.125
          int b = (grow >= cn) ? 1 : 0;
          int ln = grow - b * cn;
          int hh = gcol >> 6, dd = gcol & 63;
          of0[(((size_t)(b * H_ + hh)) * cn + ln) * 64 + dd] = vv * 0.125f;
        } else {                             // out = o@W_proj + b_proj, flag dtype
          float bvad = bF32 ? ((const float*)biasRaw)[gcol] : b2f(((const u16*)biasRaw)[gcol]);
          float ov = vv + bvad;
          if (bF32) ((float*)outRaw)[(size_t)grow * C_ + gcol] = ov;
          else      ((u16*)outRaw)[(size_t)grow * C_ + gcol] = f2b(ov);
        }
      }
    }
  }
}

// ---------------- kernel_1 = softmax_l(q . lm^T), bf16 out ----------------
__global__ __launch_bounds__(256) void k1_k(const u16* __restrict__ qb,
                                            const float* __restrict__ lm,
                                            u16* __restrict__ k1)
{
  const int bh = blockIdx.y;
  const int r0 = blockIdx.x * 64;
  __shared__ float qT[64][65];
  __shared__ float lmS[128 * 64];
  __shared__ float redA[4][64];
  __shared__ float redB[64];
  const int t = threadIdx.x;
  const u16* Q = qb + ((size_t)bh * N_ + r0) * 64;
  const float* Lm = lm + (size_t)bh * L_ * 64;
  for (int u = t; u < 2048; u += 256) ((float4*)lmS)[u] = ((const float4*)Lm)[u];
  for (int u = t; u < 512; u += 256) {
    int row = u >> 3, j0 = (u & 7) * 8;
    uint4 pk = *(const uint4*)(Q + (size_t)row * 64 + j0);
    const u16* pu = (const u16*)&pk;
    #pragma unroll
    for (int jj = 0; jj < 8; ++jj) qT[j0 + jj][row] = b2f(pu[jj]);
  }
  __syncthreads();
  const int row = t & 63, ch = t >> 6;
  float qr[64];
  #pragma unroll
  for (int j = 0; j < 64; ++j) qr[j] = qT[j][row];
  float s[32];
  for (int li = 0; li < 32; ++li) {
    const float* lp = lmS + (ch * 32 + li) * 64;
    float a = 0.f;
    #pragma unroll
    for (int j = 0; j < 64; ++j) a += lp[j] * qr[j];
    s[li] = a;
  }
  float mx = -1e30f;
  for (int li = 0; li < 32; ++li) mx = fmaxf(mx, s[li]);
  redA[ch][row] = mx;
  __syncthreads();
  if (t < 64) redB[t] = fmaxf(fmaxf(redA[0][t], redA[1][t]), fmaxf(redA[2][t], redA[3][t]));
  __syncthreads();
  mx = redB[row];
  float sum = 0.f;
  for (int li = 0; li < 32; ++li) { float e = __expf(s[li] - mx); s[li] = e; sum += e; }
  __syncthreads();
  redA[ch][row] = sum;
  __syncthreads();
  if (t < 64) redB[t] = 1.0f / (redA[0][t] + redA[1][t] + redA[2][t] + redA[3][t]);
  __syncthreads();
  const float inv = redB[row];
  u16* out = k1 + ((size_t)bh * N_ + r0 + row) * 128 + ch * 32;
  for (int li = 0; li < 32; ++li) out[li] = f2b(s[li] * inv);
}

// ---------------- kernel_2 per frame + x1 = kernel_2 @ v  (LDS-only, 3-pass) ----------------
__global__ __launch_bounds__(256) void k2x1_k(const float* __restrict__ lm,
                                              const u16* __restrict__ kb,
                                              const u16* __restrict__ vb,
                                              u16* __restrict__ x1)
{
  const int bh = blockIdx.x;
  const int f = blockIdx.y;
  __shared__ u16 kS[P_ * 64];
  __shared__ u16 vS[P_ * 64];
  __shared__ float redM[2][128];
  __shared__ float redS[2][128];
  const int t = threadIdx.x;
  const u16* Kf = kb + ((size_t)bh * N_ + f * P_) * 64;
  const u16* Vf = vb + ((size_t)bh * N_ + f * P_) * 64;
  for (int u = t; u < 1568; u += 256) {
    ((uint4*)kS)[u] = ((const uint4*)Kf)[u];
    ((uint4*)vS)[u] = ((const uint4*)Vf)[u];
  }
  __syncthreads();
  const int l = t & 127, half = t >> 7;
  const float* lp = lm + ((size_t)bh * L_ + l) * 64;
  float lr[64];
  #pragma unroll
  for (int j = 0; j < 64; ++j) lr[j] = lp[j];

  const int p0 = half * 98, p1 = p0 + 98;
  float mx = -1e30f;
  for (int p = p0; p < p1; ++p) {
    const uint4* kp = (const uint4*)(kS + p * 64);
    float s = 0.f;
    #pragma unroll
    for (int q4 = 0; q4 < 8; ++q4) {
      uint4 pk = kp[q4];
      const u32* pu = (const u32*)&pk;
      #pragma unroll
      for (int j2 = 0; j2 < 4; ++j2) {
        u32 u = pu[j2];
        s += lr[q4 * 8 + j2 * 2] * lo16f(u) + lr[q4 * 8 + j2 * 2 + 1] * hi16f(u);
      }
    }
    mx = fmaxf(mx, s);
  }
  redM[half][l] = mx;
  __syncthreads();
  mx = fmaxf(redM[0][l], redM[1][l]);

  float sm = 0.f;
  for (int p = p0; p < p1; ++p) {
    const uint4* kp = (const uint4*)(kS + p * 64);
    float s = 0.f;
    #pragma unroll
    for (int q4 = 0; q4 < 8; ++q4) {
      uint4 pk = kp[q4];
      const u32* pu = (const u32*)&pk;
      #pragma unroll
      for (int j2 = 0; j2 < 4; ++j2) {
        u32 u = pu[j2];
        s += lr[q4 * 8 + j2 * 2] * lo16f(u) + lr[q4 * 8 + j2 * 2 + 1] * hi16f(u);
      }
    }
    sm += __expf(s - mx);
  }
  redS[half][l] = sm;
  __syncthreads();
  const float inv = 1.0f / (redS[0][l] + redS[1][l]);

  const int dd0 = half * 32;
  float acc[32];
  #pragma unroll
  for (int u = 0; u < 32; ++u) acc[u] = 0.f;
  for (int p = 0; p < P_; ++p) {
    const uint4* kp = (const uint4*)(kS + p * 64);
    float s = 0.f;
    #pragma unroll
    for (int q4 = 0; q4 < 8; ++q4) {
      uint4 pk = kp[q4];
      const u32* pu = (const u32*)&pk;
      #pragma unroll
      for (int j2 = 0; j2 < 4; ++j2) {
        u32 u = pu[j2];
        s += lr[q4 * 8 + j2 * 2] * lo16f(u) + lr[q4 * 8 + j2 * 2 + 1] * hi16f(u);
      }
    }
    const float e = __expf(s - mx);
    const uint4* vp = (const uint4*)(vS + p * 64 + dd0);
    #pragma unroll
    for (int q4 = 0; q4 < 4; ++q4) {
      uint4 pv = vp[q4];
      const u32* pu = (const u32*)&pv;
      #pragma unroll
      for (int j2 = 0; j2 < 4; ++j2) {
        u32 u = pu[j2];
        acc[q4 * 8 + j2 * 2]     += e * lo16f(u);
        acc[q4 * 8 + j2 * 2 + 1] += e * hi16f(u);
      }
    }
  }
  u16* out = x1 + (((size_t)bh * L_ + l) * F_ + f) * 64 + dd0;
  for (int u = 0; u < 32; ++u) out[u] = f2b(acc[u] * inv);
}

// ---------------- final 16-way frame attention + o = attn @ v2 (chunked) ----------------
__global__ __launch_bounds__(256) void attn_k(const float* __restrict__ q2c,
                                              const u16* __restrict__ k2c,
                                              const u16* __restrict__ v2c,
                                              int n0c, int cn, const int* __restrict__ flagp,
                                              void* __restrict__ outRaw,
                                              u16* __restrict__ o)
{
  const int bh = blockIdx.y;
  const int b = bh / H_, hh = bh - b * H_;
  const int t = threadIdx.x;
  const int f32o = flagp[0];
  __shared__ float aS[64][17];
  const int nl = t >> 2, qi = t & 3;
  const int ln = blockIdx.x * 64 + nl;
  const bool act = ln < cn;
  const int n = n0c + ln;
  float q[64];
  if (act) {
    const float* qr = q2c + ((size_t)bh * cn + ln) * 64;
    #pragma unroll
    for (int j = 0; j < 64; ++j) q[j] = qr[j];
    float lg[4];
    #pragma unroll
    for (int ff = 0; ff < 4; ++ff) {
      const int f = qi * 4 + ff;
      const u16* kp = k2c + (((size_t)bh * cn + ln) * F_ + f) * 64;
      float s = 0.f;
      #pragma unroll
      for (int j8 = 0; j8 < 8; ++j8) {
        uint4 pk = ((const uint4*)kp)[j8];
        const u16* pu = (const u16*)&pk;
        #pragma unroll
        for (int u = 0; u < 8; ++u) s += q[j8 * 8 + u] * b2f(pu[u]);
      }
      lg[ff] = s;
    }
    float mx = fmaxf(fmaxf(lg[0], lg[1]), fmaxf(lg[2], lg[3]));
    mx = fmaxf(mx, __shfl_xor(mx, 1));
    mx = fmaxf(mx, __shfl_xor(mx, 2));
    float e[4], sm = 0.f;
    #pragma unroll
    for (int ff = 0; ff < 4; ++ff) { e[ff] = __expf(lg[ff] - mx); sm += e[ff]; }
    sm += __shfl_xor(sm, 1);
    sm += __shfl_xor(sm, 2);
    const float iv = 1.0f / sm;
    const size_t abase = ((size_t)bh * N_ + n) * F_ + qi * 4;
    #pragma unroll
    for (int ff = 0; ff < 4; ++ff) {
      const float a = e[ff] * iv;
      if (f32o) ((float*)outRaw)[OUTPART_ + abase + ff] = a;
      else      ((u16*)outRaw)[OUTPART_ + abase + ff] = f2b(a);
      aS[nl][qi * 4 + ff] = a;
    }
  }
  __syncthreads();
  if (act) {
    const int dd0 = qi * 16;
    float acc[16];
    #pragma unroll
    for (int u = 0; u < 16; ++u) acc[u] = 0.f;
    for (int f = 0; f < F_; ++f) {
      const float w2 = aS[nl][f];
      const u16* vp = v2c + (((size_t)bh * cn + ln) * F_ + f) * 64 + dd0;
      uint4 pv0 = ((const uint4*)vp)[0], pv1 = ((const uint4*)vp)[1];
      const u16* pu0 = (const u16*)&pv0;
      const u16* pu1 = (const u16*)&pv1;
      #pragma unroll
      for (int u = 0; u < 8; ++u) acc[u] += w2 * b2f(pu0[u]);
      #pragma unroll
      for (int u = 0; u < 8; ++u) acc[8 + u] += w2 * b2f(pu1[u]);
    }
    u16* op = o + ((size_t)(b * N_ + n)) * C_ + hh * 64 + dd0;
    for (int u = 0; u < 16; ++u) op[u] = f2b(acc[u]);
  }
}

extern "C" void kernel_launch(void* const* d_in, const int* in_sizes, int n_in,
                              void* d_out, int out_size, void* d_ws, size_t ws_size,
                              hipStream_t stream)
{
  (void)in_sizes; (void)n_in; (void)out_size;
  const void* x     = d_in[0];
  const void* Wqkv  = d_in[1];
  const void* Wpq   = d_in[2];
  const void* Wpkv  = d_in[3];
  const void* Wproj = d_in[4];
  const void* bproj = d_in[5];

  char* ws = (char*)d_ws;
  size_t off = 0;
  auto alloc = [&](size_t bytes) { void* p = ws + off; off += (bytes + 255) & ~(size_t)255; return p; };
  int*  flagp = (int*)alloc(256);
  u16*  qb  = (u16*)alloc(9633792);     // (bh,N,64) bf16, scaled
  u16*  kb  = (u16*)alloc(9633792);     // scaled
  u16*  vb  = (u16*)alloc(9633792);
  float* lm = (float*)alloc(786432);    // (bh,128,64) f32
  u16*  x1b = (u16*)alloc(6291456);     // (bh,128,16,64) bf16
  u16*  ob  = (u16*)alloc(9633792);     // (B,N,C) bf16
  const size_t k1off = off;             // qT f32 starts here (aliases k1b + chunk region)
  u16*  k1b = (u16*)alloc(19267584);    // (bh,N,128) bf16
  const size_t chunk0 = off;

  // qT (selection f32, transposed [bh][64][N]) needs 19,267,584 B at k1off;
  // dead before k1b & chunk region live
  const size_t qtNeed = k1off + 19267584 + 256;

  int Nc = 0;
  {
    const int cands[5] = {3136, 1568, 784, 392, 196};
    for (int i = 0; i < 5; ++i) {
      size_t need = chunk0 + (size_t)156672 * cands[i] + 1024;
      if (need <= ws_size && qtNeed <= ws_size) { Nc = cands[i]; break; }
    }
  }
  if (Nc == 0) return;  // ws floor ~95.7 MB
  const int nchunks = N_ / Nc;
  u16*  xoc = (u16*)(ws + chunk0);                // (B,Nc,F,C) bf16
  u16*  k2c = xoc + (size_t)24576 * Nc;           // (B,h,Nc,F,d) bf16
  u16*  v2c = k2c + (size_t)24576 * Nc;
  u16*  xdc = v2c + (size_t)24576 * Nc;           // (B,Nc,C) bf16
  float* q2c = (float*)(xdc + (size_t)1536 * Nc); // (B,h,Nc,d) f32
  float* qt  = (float*)(ws + k1off);              // selection-grade f32 qT (dead before k1_k)

  // dtype sniff on W_qkv
  detect_k<<<1, 64, 0, stream>>>((const u32*)Wqkv, flagp);

  // selection-grade f32 qT (transposed), then coalesced greedy landmarks
  qselT_k<<<dim3(98, 12), 256, 0, stream>>>(x, Wqkv, flagp, qt);
  landmarksT_k<<<24, 512, 0, stream>>>(qt, lm);

  // qkv projection -> qb,kb,vb (bf16 smooth path)
  gemm_k<0><<<dim3(49, 18, 1), 256, 0, stream>>>(x, Wqkv, 6272, 768, 768, 2304, 0, 0, flagp,
                                                 nullptr, qb, kb, vb, nullptr, nullptr);
  // kernel_2 + x1 (LDS-only)
  k2x1_k<<<dim3(24, 16), 256, 0, stream>>>(lm, kb, vb, x1b);
  // kernel_1 (overwrites qT region — qT dead)
  k1_k<<<dim3(49, 24), 256, 0, stream>>>(qb, lm, k1b);

  for (int c = 0; c < nchunks; ++c) {
    const int n0c = c * Nc;
    gemm_k<1><<<dim3((Nc + 127) / 128, 8, 24), 256, 0, stream>>>(
        k1b, x1b, Nc, 128, 128, 1024, n0c, Nc, flagp, nullptr, xoc, xdc, nullptr, nullptr, nullptr);
    gemm_k<2><<<dim3((2 * Nc * 16) / 128, 12, 1), 256, 0, stream>>>(
        xoc, Wpkv, 2 * Nc * 16, 768, 768, 1536, n0c, Nc, flagp, nullptr, k2c, v2c, nullptr, nullptr, nullptr);
    gemm_k<3><<<dim3((2 * Nc + 127) / 128, 6, 1), 256, 0, stream>>>(
        xdc, Wpq, 2 * Nc, 768, 768, 768, n0c, Nc, flagp, q2c, nullptr, nullptr, nullptr, nullptr, nullptr);
    attn_k<<<dim3((Nc + 63) / 64, 24), 256, 0, stream>>>(
        q2c, k2c, v2c, n0c, Nc, flagp, d_out, ob);
  }
  // out = o @ W_proj + b_proj
  gemm_k<4><<<dim3(49, 6, 1), 256, 0, stream>>>(ob, Wproj, 6272, 768, 768, 768, 0, 0, flagp,
                                                nullptr, nullptr, nullptr, nullptr, bproj, d_out);
}